// Round 12
// baseline (465.233 us; speedup 1.0000x reference)
//
#include <hip/hip_runtime.h>
#include <math.h>

// Problem constants
#define NROWS 16384   // 32*512
#define H     768
#define KEXP  6912    // 768 (silu*base_w) + 768*8 (bases*spline_w*scaler)
#define NCHUNK 108    // KEXP/64 K-steps
#define NITER 54      // 2 K-steps per iteration

typedef __attribute__((ext_vector_type(8))) short  bhalf8;
typedef __attribute__((ext_vector_type(4))) float  floatx4;
typedef __attribute__((ext_vector_type(4))) unsigned int uintx4;

__device__ __forceinline__ unsigned short f2bf(float f) {
    unsigned int u = __float_as_uint(f);
    u = (u + 0x7FFFu + ((u >> 16) & 1u)) >> 16;   // RNE
    return (unsigned short)u;
}
__device__ __forceinline__ float bf2f(unsigned short h) {
    return __uint_as_float(((unsigned int)h) << 16);
}
__device__ __forceinline__ unsigned int pack2(unsigned short a, unsigned short b) {
    return (unsigned int)a | ((unsigned int)b << 16);
}
// silu via fast rcp (v_rcp_f32 ~1e-7 rel err)
__device__ __forceinline__ float silu_f(float x) {
    return x * __builtin_amdgcn_rcpf(1.0f + __expf(-x));
}

// Branch-free tanh-form GELU (|err vs exact erf-GELU| < ~1e-3 in u), fast rcp
__device__ __forceinline__ float gelu_fast(float x) {
    float x3 = x * x * x;
    float y = fmaf(x3, 0.0356774081f, x * 0.7978845608f);
    float e = __expf(2.0f * y);
    float th = 1.0f - 2.0f * __builtin_amdgcn_rcpf(e + 1.0f);
    return 0.5f * x * (1.0f + th);
}

// Closed-form cubic B-spline bases on uniform knots g[j] = (j-3)*0.4 - 1.
__device__ __forceinline__ void kan_bases(float x, float* __restrict__ b) {
    const float c6 = 0.166666666667f;
    float u  = fmaf(x, 2.5f, 5.5f);
    float fj = floorf(u);
    float t  = u - fj;
    int  j0  = (int)fj;
    float t2 = t * t, t3 = t2 * t;
    float n0 = t3 * c6;
    float n1 = fmaf(t3, -0.5f, fmaf(t2, 0.5f, fmaf(t, 0.5f, c6)));
    float n2 = fmaf(t3, 0.5f, fmaf(t2, -1.0f, 0.666666666667f));
    float omt = 1.0f - t;
    float n3 = omt * omt * omt * c6;
#pragma unroll
    for (int c = 0; c < 8; ++c) {
        int d = j0 - c;
        float v = (d == 0) ? n0 : 0.0f;
        v = (d == 1) ? n1 : v;
        v = (d == 2) ? n2 : v;
        v = (d == 3) ? n3 : v;
        b[c] = v;
    }
}

// ---- prep_expand: ROUND-10 VERBATIM (r11's expand_granule variant was +17us —
//      reverted). Flat scalar, lane-consecutive nt stores, select-chain bases.
__global__ __launch_bounds__(256) void prep_expand(
    const float* __restrict__ x, const float* __restrict__ bw,
    const float* __restrict__ sw, const float* __restrict__ sc,
    unsigned short* __restrict__ wp, unsigned short* __restrict__ F)
{
    const int b = blockIdx.x, t = threadIdx.x;
    if (b < 6144) {
        const int e0 = b * 2048 + t;
#pragma unroll
        for (int j = 0; j < 8; ++j) {
            int e = e0 + j * 256;
            int n = e / 768;                      // magic-mul
            int i = e - n * 768;
            float xv = x[e];                      // x row-major (N,768): linear in e
            unsigned short* out = F + (size_t)n * KEXP;
            __builtin_nontemporal_store(f2bf(silu_f(xv)), out + i);   // 2B, lane-consec
            float bb[8];
            kan_bases(xv, bb);
            uintx4 pk;
            pk.x = pack2(f2bf(bb[0]), f2bf(bb[1]));
            pk.y = pack2(f2bf(bb[2]), f2bf(bb[3]));
            pk.z = pack2(f2bf(bb[4]), f2bf(bb[5]));
            pk.w = pack2(f2bf(bb[6]), f2bf(bb[7]));
            __builtin_nontemporal_store(pk, (uintx4*)(out + H + (size_t)i * 8)); // 16B
        }
    } else {
        const int n = b - 6144;
        const float* bwr = bw + (size_t)n * H;
        unsigned short* out = wp + (size_t)n * KEXP;
        if (t < 96) {
            const float4* xp = (const float4*)(bwr + t * 8);
            float4 v0 = xp[0], v1 = xp[1];
            uintx4 pk;
            pk.x = pack2(f2bf(v0.x), f2bf(v0.y));
            pk.y = pack2(f2bf(v0.z), f2bf(v0.w));
            pk.z = pack2(f2bf(v1.x), f2bf(v1.y));
            pk.w = pack2(f2bf(v1.z), f2bf(v1.w));
            __builtin_nontemporal_store(pk, (uintx4*)(out + t * 8));
        }
#pragma unroll
        for (int p = 0; p < 3; ++p) {
            int i = t + p * 256;
            float s = sc[(size_t)n * H + i];
            const float4* swp = (const float4*)(sw + ((size_t)n * H + i) * 8);
            float4 w0 = swp[0], w1 = swp[1];
            uintx4 pk;
            pk.x = pack2(f2bf(w0.x * s), f2bf(w0.y * s));
            pk.y = pack2(f2bf(w0.z * s), f2bf(w0.w * s));
            pk.z = pack2(f2bf(w1.x * s), f2bf(w1.y * s));
            pk.w = pack2(f2bf(w1.z * s), f2bf(w1.w * s));
            __builtin_nontemporal_store(pk, (uintx4*)(out + H + (size_t)i * 8));
        }
    }
}

// ==== Layer 1+2 fused: r2 K-loop VERBATIM + LDS-GATHER epilogue.
// r11 lesson (spill tripwire WRITE_SIZE 16->207MB): funnel-shift bases spilled.
// New epilogue: weights GATHERED by basis index instead of bases scattered to
// 8 slots. sc-folded table in LDS (sA reused after K-loop; [g][ipad1024][o]
// f32, 64KB; ds_read_b64 fetches both outputs; banks 2*lm -> conflict-free;
// quad lanes broadcast). Domain: u=gelu>=-0.171 => j0>=5 => g>=2; only upper
// mask g<=7 needed (address med3-clamped for safety). ~65 ops/elem vs ~140.
// CRITICAL: vmcnt(0)+syncthreads before table staging — tail DMA loads from
// the K-loop still target sA.

#define AS1 __attribute__((address_space(1)))
#define AS3 __attribute__((address_space(3)))

#define DSR(D, A, O) asm volatile("ds_read_b128 %0, %1 offset:" #O : "=v"(D) : "v"(A) : "memory")
#define LDA0(O) do{ DSR(fA0[0],avA[0],O); DSR(fA0[1],avA[1],O); DSR(fA0[2],avA[2],O); DSR(fA0[3],avA[3],O); \
                    DSR(fA0[4],avA[4],O); DSR(fA0[5],avA[5],O); DSR(fA0[6],avA[6],O); DSR(fA0[7],avA[7],O); }while(0)
#define LDA1(O) do{ DSR(fA1[0],avA[0],O); DSR(fA1[1],avA[1],O); DSR(fA1[2],avA[2],O); DSR(fA1[3],avA[3],O); \
                    DSR(fA1[4],avA[4],O); DSR(fA1[5],avA[5],O); DSR(fA1[6],avA[6],O); DSR(fA1[7],avA[7],O); }while(0)
#define LDB(O)  do{ DSR(fB[0],avB[0],O); DSR(fB[1],avB[1],O); }while(0)

#define MM0(QN) do{ \
    _Pragma("unroll") \
    for (int kk = 0; kk < 2; ++kk) \
        _Pragma("unroll") \
        for (int im = 0; im < 4; ++im) \
            acc0[QN][im] = __builtin_amdgcn_mfma_f32_16x16x32_bf16( \
                fA0[im*2+kk], fB[kk], acc0[QN][im], 0, 0, 0); \
}while(0)
#define MM1(QN) do{ \
    _Pragma("unroll") \
    for (int kk = 0; kk < 2; ++kk) \
        _Pragma("unroll") \
        for (int im = 0; im < 4; ++im) \
            acc1[QN][im] = __builtin_amdgcn_mfma_f32_16x16x32_bf16( \
                fA1[im*2+kk], fB[kk], acc1[QN][im], 0, 0, 0); \
}while(0)

#define STG_A(BF,HH,KS) do{ \
    __builtin_amdgcn_global_load_lds((const AS1 void*)(pA##HH[0] + (size_t)(KS)*64), \
        (AS3 void*)&sA[BF][HH][wb8], 16, 0, 0); \
    __builtin_amdgcn_global_load_lds((const AS1 void*)(pA##HH[1] + (size_t)(KS)*64), \
        (AS3 void*)&sA[BF][HH][4096 + wb8], 16, 0, 0); \
}while(0)
#define STG_B(BF,QN,KS) \
    __builtin_amdgcn_global_load_lds((const AS1 void*)(pB[QN] + (size_t)(KS)*64), \
        (AS3 void*)&sB[BF][QN][wb8], 16, 0, 0)

#define PH_MID do{ __builtin_amdgcn_s_barrier(); \
    asm volatile("s_waitcnt lgkmcnt(0)" ::: "memory"); \
    __builtin_amdgcn_sched_barrier(0); \
    __builtin_amdgcn_s_setprio(1); }while(0)
#define PH_END do{ __builtin_amdgcn_s_setprio(0); \
    __builtin_amdgcn_sched_barrier(0); \
    __builtin_amdgcn_s_barrier(); }while(0)
#define PH_END_VMN(N) do{ __builtin_amdgcn_s_setprio(0); \
    __builtin_amdgcn_sched_barrier(0); \
    asm volatile("s_waitcnt vmcnt(" #N ")" ::: "memory"); \
    __builtin_amdgcn_s_barrier(); }while(0)

// One gather term: basis slot g gets polynomial value ND (slot c=j0-d).
// wt2 indexed in float2 units: (g<<10) + iw  -> both outputs' folded weights.
#define GATH(ND, GEXPR) do{ \
    int g_ = (GEXPR); \
    int gc_ = (g_ < 0) ? 0 : ((g_ > 7) ? 7 : g_); \
    float2 w_ = wt2[((unsigned)gc_ << 10) + (unsigned)iw]; \
    float ndm_ = (g_ <= 7) ? (ND) : 0.0f; \
    pa_ = fmaf(ndm_, w_.x, pa_); \
    pb_ = fmaf(ndm_, w_.y, pb_); \
}while(0)

// One qm-half: gather-based spline dot + base term, reduce, atomic.
#define EPI_HALF(ACC, QMOFF) do{ \
    float pa[4][4] = {}, pb[4][4] = {}; \
    _Pragma("unroll") \
    for (int qn = 0; qn < 3; ++qn) { \
        const int iw = colBase + qn*64 + wc*16 + lm; \
        const float bwa = bw2[iw], bwb = bw2[H + iw]; \
        _Pragma("unroll") \
        for (int im = 0; im < 4; ++im) \
        _Pragma("unroll") \
        for (int rg = 0; rg < 4; ++rg) { \
            float u = gelu_fast(ACC[qn][im][rg]); \
            float f0v = silu_f(u); \
            float uu = fmaf(u, 2.5f, 5.5f); \
            float fj = floorf(uu); \
            float tt = uu - fj; \
            int j0 = (int)fj; \
            float tq = tt * tt, tc = tq * tt; \
            float n0 = tc * 0.166666666667f; \
            float n1 = fmaf(tc, -0.5f, fmaf(tq, 0.5f, fmaf(tt, 0.5f, 0.166666666667f))); \
            float n2 = fmaf(tc, 0.5f, fmaf(tq, -1.0f, 0.666666666667f)); \
            float omt = 1.0f - tt; \
            float n3 = omt * omt * omt * 0.166666666667f; \
            float pa_ = 0.f, pb_ = 0.f; \
            GATH(n0, j0); GATH(n1, j0 - 1); GATH(n2, j0 - 2); GATH(n3, j0 - 3); \
            pa[im][rg] += fmaf(f0v, bwa, pa_); \
            pb[im][rg] += fmaf(f0v, bwb, pb_); \
        } \
    } \
    _Pragma("unroll") \
    for (int im = 0; im < 4; ++im) \
    _Pragma("unroll") \
    for (int rg = 0; rg < 4; ++rg) { \
        float a0 = pa[im][rg], a1 = pb[im][rg]; \
        _Pragma("unroll") \
        for (int off = 8; off > 0; off >>= 1) { \
            a0 += __shfl_xor(a0, off, 64); \
            a1 += __shfl_xor(a1, off, 64); \
        } \
        if (lm == 0) { \
            const int row = rowBase + (QMOFF) + wr*64 + im*16 + quad*4 + rg; \
            atomicAdd(&outp[(size_t)row * 2 + 0], a0); \
            atomicAdd(&outp[(size_t)row * 2 + 1], a1); \
        } \
    } \
}while(0)

__global__ __launch_bounds__(512, 1) void kan1_fused(
    const unsigned short* __restrict__ F, const unsigned short* __restrict__ wp,
    const float* __restrict__ bw2, const float* __restrict__ sw2,
    const float* __restrict__ sc2, float* __restrict__ outp)
{
    __shared__ __align__(16) unsigned short sA[2][2][8192];  // [buf][half 128rows][128*64]
    __shared__ __align__(16) unsigned short sB[2][3][4096];  // [buf][third 64rows][64*64]

    const int b = blockIdx.x;                  // 0..255
    const int s = b >> 3;
    const int rowT = (b & 7) * 8 + (s >> 2);   // 0..63
    const int colT = s & 3;                    // 0..3
    const int rowBase = rowT * 256, colBase = colT * 192;

    const int t = threadIdx.x;
    const int lane = t & 63;
    const int quad = lane >> 4, lm = lane & 15, p7 = lane & 7;
    const int wv = t >> 6, wr = wv & 1, wc = wv >> 1;   // 2M x 4N wave grid

    const int rr = t >> 3;                    // 0..63
    const int slotx = (t & 7) ^ (rr & 7);
    const int wb8 = (t & 448) * 8;            // wave-uniform LDS elem base (wv*512)

    const unsigned short* pA0[2]; const unsigned short* pA1[2];
    const unsigned short* pB[3];
#pragma unroll
    for (int p = 0; p < 2; ++p) {
        pA0[p] = F + (size_t)(rowBase +       p*64 + rr) * KEXP + slotx*8;
        pA1[p] = F + (size_t)(rowBase + 128 + p*64 + rr) * KEXP + slotx*8;
    }
#pragma unroll
    for (int q = 0; q < 3; ++q)
        pB[q] = wp + (size_t)(colBase + q*64 + rr) * KEXP + slotx*8;

    unsigned int avA[8], avB[2];
    {
        unsigned int aB = (unsigned int)(size_t)(AS3 unsigned short*)&sA[0][0][0];
        unsigned int bB = (unsigned int)(size_t)(AS3 unsigned short*)&sB[0][0][0];
#pragma unroll
        for (int im = 0; im < 4; ++im)
#pragma unroll
            for (int kk = 0; kk < 2; ++kk)
                avA[im*2+kk] = aB + (unsigned)(((wr*64 + im*16 + lm)*64 + (((kk*4+quad)^p7)*8)) * 2);
#pragma unroll
        for (int kk = 0; kk < 2; ++kk)
            avB[kk] = bB + (unsigned)(((wc*16 + lm)*64 + (((kk*4+quad)^p7)*8)) * 2);
    }

    floatx4 acc0[3][4] = {};   // [qn][im], qm=0 rows
    floatx4 acc1[3][4] = {};   // qm=1 rows
    bhalf8 fA0[8], fA1[8], fB[2];

    // prologue: buf0 <- ks0 (7 loads), buf1 <- ks1 minus B2 (6 loads); retire 5
    STG_A(0,0,0); STG_A(0,1,0); STG_B(0,0,0); STG_B(0,1,0); STG_B(0,2,0);
    STG_A(1,0,1); STG_A(1,1,1); STG_B(1,0,1); STG_B(1,1,1);
    asm volatile("s_waitcnt vmcnt(8)" ::: "memory");
    __builtin_amdgcn_s_barrier();

#pragma unroll 1
    for (int i = 0; i < NITER; ++i) {
        const int k1 = 2*i + 1;
        const int k2 = (2*i + 2 > 107) ? 107 : 2*i + 2;
        const int k3 = (2*i + 3 > 107) ? 107 : 2*i + 3;
        // K-step 2i from buf0
        LDA0(0);     LDB(0);     STG_B(1,2,k1);               PH_MID; MM0(0);         PH_END_VMN(10);
        LDA1(16384);             STG_A(0,0,k2);               PH_MID; MM1(0);         PH_END_VMN(10);
        LDB(8192);               STG_A(0,1,k2);               PH_MID; MM1(1); MM0(1); PH_END_VMN(11);
        LDB(16384);              STG_B(0,0,k2); STG_B(0,1,k2);PH_MID; MM0(2); MM1(2); PH_END_VMN(8);
        // K-step 2i+1 from buf1
        LDA0(32768); LDB(24576); STG_B(0,2,k2);               PH_MID; MM0(0);         PH_END;
        LDA1(49152);             STG_A(1,0,k3);               PH_MID; MM1(0);         PH_END_VMN(10);
        LDB(32768);              STG_A(1,1,k3);               PH_MID; MM1(1); MM0(1); PH_END_VMN(11);
        LDB(40960);              STG_B(1,0,k3); STG_B(1,1,k3);PH_MID; MM0(2); MM1(2); PH_END_VMN(8);
    }

    // ---- stage sc-folded layer-2 weight table into LDS (sA reused, 64KB) ----
    // MUST drain tail DMA loads first: up to 8 global_load_lds still in flight
    // target sA/sB. Layout [g][ipad 1024][o] f32: float2 index (g<<10) + i.
    asm volatile("s_waitcnt vmcnt(0)" ::: "memory");
    __syncthreads();
    {
        float* wt = (float*)&sA[0][0][0];
#pragma unroll
        for (int c = 0; c < 32; ++c) {
            int lin = t + c * 512;            // 0..16383 = g*2048 + i*2 + o
            int g   = lin >> 11;
            int rem = lin & 2047;
            int iw  = rem >> 1, o = rem & 1;
            float v = 0.0f;
            if (iw < H) v = sw2[((size_t)o * H + iw) * 8 + g] * sc2[(size_t)o * H + iw];
            wt[lin] = v;
        }
    }
    __syncthreads();
    const float2* wt2 = (const float2*)&sA[0][0][0];

    // ---- fused layer-2 epilogue: gather weights by basis index ----
    EPI_HALF(acc0, 0);
    EPI_HALF(acc1, 128);
}

extern "C" void kernel_launch(void* const* d_in, const int* in_sizes, int n_in,
                              void* d_out, int out_size, void* d_ws, size_t ws_size,
                              hipStream_t stream) {
    const float* hidden = (const float*)d_in[0];
    const float* bw1    = (const float*)d_in[1];
    const float* sw1    = (const float*)d_in[2];
    const float* sc1    = (const float*)d_in[3];
    const float* bw2    = (const float*)d_in[4];
    const float* sw2    = (const float*)d_in[5];
    const float* sc2    = (const float*)d_in[6];
    float* out = (float*)d_out;

    const size_t wp_elems = (size_t)H * KEXP;      // 10.6 MB bf16
    unsigned short* wp = (unsigned short*)d_ws;
    unsigned short* F  = wp + wp_elems;            // 226.5 MB bf16

    hipMemsetAsync(d_out, 0, (size_t)out_size, stream);   // graph-capturable
    prep_expand<<<6144 + H, 256, 0, stream>>>(hidden, bw1, sw1, sc1, wp, F);
    kan1_fused<<<256, 512, 0, stream>>>(F, wp, bw2, sw2, sc2, out);
}

// Round 13
// 313.804 us; speedup vs baseline: 1.4826x; 1.4826x over previous
//
#include <hip/hip_runtime.h>
#include <math.h>

// Problem constants
#define NROWS 16384   // 32*512
#define H     768
#define KEXP  6912    // 768 (silu*base_w) + 768*8 (bases*spline_w*scaler)
#define NCHUNK 108    // KEXP/64 K-steps
#define NITER 54      // 2 K-steps per iteration

typedef __attribute__((ext_vector_type(8))) short  bhalf8;
typedef __attribute__((ext_vector_type(4))) float  floatx4;
typedef __attribute__((ext_vector_type(4))) unsigned int uintx4;

__device__ __forceinline__ unsigned short f2bf(float f) {
    unsigned int u = __float_as_uint(f);
    u = (u + 0x7FFFu + ((u >> 16) & 1u)) >> 16;   // RNE
    return (unsigned short)u;
}
__device__ __forceinline__ float bf2f(unsigned short h) {
    return __uint_as_float(((unsigned int)h) << 16);
}
__device__ __forceinline__ unsigned int pack2(unsigned short a, unsigned short b) {
    return (unsigned int)a | ((unsigned int)b << 16);
}
// silu via fast rcp (v_rcp_f32 ~1e-7 rel err)
__device__ __forceinline__ float silu_f(float x) {
    return x * __builtin_amdgcn_rcpf(1.0f + __expf(-x));
}

// Branch-free tanh-form GELU (|err vs exact erf-GELU| < ~1e-3 in u), fast rcp
__device__ __forceinline__ float gelu_fast(float x) {
    float x3 = x * x * x;
    float y = fmaf(x3, 0.0356774081f, x * 0.7978845608f);
    float e = __expf(2.0f * y);
    float th = 1.0f - 2.0f * __builtin_amdgcn_rcpf(e + 1.0f);
    return 0.5f * x * (1.0f + th);
}

// Closed-form cubic B-spline bases on uniform knots g[j] = (j-3)*0.4 - 1.
// SELECT-CHAIN FORM: the only epilogue/prep basis form that does NOT spill.
// (r11 funnel-shift: WRITE_SIZE 16->207MB scratch; r12 LDS-gather: 390MB
//  scratch + 1.57M bank conflicts. Both reverted. Do not re-attempt without
//  checking WRITE_SIZE.)
__device__ __forceinline__ void kan_bases(float x, float* __restrict__ b) {
    const float c6 = 0.166666666667f;
    float u  = fmaf(x, 2.5f, 5.5f);
    float fj = floorf(u);
    float t  = u - fj;
    int  j0  = (int)fj;
    float t2 = t * t, t3 = t2 * t;
    float n0 = t3 * c6;
    float n1 = fmaf(t3, -0.5f, fmaf(t2, 0.5f, fmaf(t, 0.5f, c6)));
    float n2 = fmaf(t3, 0.5f, fmaf(t2, -1.0f, 0.666666666667f));
    float omt = 1.0f - t;
    float n3 = omt * omt * omt * c6;
#pragma unroll
    for (int c = 0; c < 8; ++c) {
        int d = j0 - c;
        float v = (d == 0) ? n0 : 0.0f;
        v = (d == 1) ? n1 : v;
        v = (d == 2) ? n2 : v;
        v = (d == 3) ? n3 : v;
        b[c] = v;
    }
}

// ---- prep_expand: ROUND-10 VERBATIM (best of 4 measured implementations).
//      Flat scalar, 8 STRIDED elems/thread (lane-consecutive stores), nt
//      stores. r6 float4 variant de-coalesced stores (-35%); r11 funnel was
//      +17us. ~112us ≈ 1.4x a plausible HBM-write-asymmetry floor.
__global__ __launch_bounds__(256) void prep_expand(
    const float* __restrict__ x, const float* __restrict__ bw,
    const float* __restrict__ sw, const float* __restrict__ sc,
    unsigned short* __restrict__ wp, unsigned short* __restrict__ F)
{
    const int b = blockIdx.x, t = threadIdx.x;
    if (b < 6144) {
        const int e0 = b * 2048 + t;
#pragma unroll
        for (int j = 0; j < 8; ++j) {
            int e = e0 + j * 256;
            int n = e / 768;                      // magic-mul
            int i = e - n * 768;
            float xv = x[e];                      // x row-major (N,768): linear in e
            unsigned short* out = F + (size_t)n * KEXP;
            __builtin_nontemporal_store(f2bf(silu_f(xv)), out + i);   // 2B, lane-consec
            float bb[8];
            kan_bases(xv, bb);
            uintx4 pk;
            pk.x = pack2(f2bf(bb[0]), f2bf(bb[1]));
            pk.y = pack2(f2bf(bb[2]), f2bf(bb[3]));
            pk.z = pack2(f2bf(bb[4]), f2bf(bb[5]));
            pk.w = pack2(f2bf(bb[6]), f2bf(bb[7]));
            __builtin_nontemporal_store(pk, (uintx4*)(out + H + (size_t)i * 8)); // 16B
        }
    } else {
        const int n = b - 6144;
        const float* bwr = bw + (size_t)n * H;
        unsigned short* out = wp + (size_t)n * KEXP;
        if (t < 96) {
            const float4* xp = (const float4*)(bwr + t * 8);
            float4 v0 = xp[0], v1 = xp[1];
            uintx4 pk;
            pk.x = pack2(f2bf(v0.x), f2bf(v0.y));
            pk.y = pack2(f2bf(v0.z), f2bf(v0.w));
            pk.z = pack2(f2bf(v1.x), f2bf(v1.y));
            pk.w = pack2(f2bf(v1.z), f2bf(v1.w));
            __builtin_nontemporal_store(pk, (uintx4*)(out + t * 8));
        }
#pragma unroll
        for (int p = 0; p < 3; ++p) {
            int i = t + p * 256;
            float s = sc[(size_t)n * H + i];
            const float4* swp = (const float4*)(sw + ((size_t)n * H + i) * 8);
            float4 w0 = swp[0], w1 = swp[1];
            uintx4 pk;
            pk.x = pack2(f2bf(w0.x * s), f2bf(w0.y * s));
            pk.y = pack2(f2bf(w0.z * s), f2bf(w0.w * s));
            pk.z = pack2(f2bf(w1.x * s), f2bf(w1.y * s));
            pk.w = pack2(f2bf(w1.z * s), f2bf(w1.w * s));
            __builtin_nontemporal_store(pk, (uintx4*)(out + H + (size_t)i * 8));
        }
    }
}

// ==== Layer 1+2 fused: ROUND-10 VERBATIM (measured best: 192.7us, total 307.8).
// K-loop: r2 4-phase counted-vmcnt schedule (measured floor 155us; 8-phase,
// 3-phase, fused-expansion all regressed). Epilogue: qn-outer select-chain,
// two sequential per-half passes (the only non-spilling form; WRITE_SIZE=16MB
// is the tripwire — r11/r12 alternatives hit 207/390MB scratch).

#define AS1 __attribute__((address_space(1)))
#define AS3 __attribute__((address_space(3)))

#define DSR(D, A, O) asm volatile("ds_read_b128 %0, %1 offset:" #O : "=v"(D) : "v"(A) : "memory")
#define LDA0(O) do{ DSR(fA0[0],avA[0],O); DSR(fA0[1],avA[1],O); DSR(fA0[2],avA[2],O); DSR(fA0[3],avA[3],O); \
                    DSR(fA0[4],avA[4],O); DSR(fA0[5],avA[5],O); DSR(fA0[6],avA[6],O); DSR(fA0[7],avA[7],O); }while(0)
#define LDA1(O) do{ DSR(fA1[0],avA[0],O); DSR(fA1[1],avA[1],O); DSR(fA1[2],avA[2],O); DSR(fA1[3],avA[3],O); \
                    DSR(fA1[4],avA[4],O); DSR(fA1[5],avA[5],O); DSR(fA1[6],avA[6],O); DSR(fA1[7],avA[7],O); }while(0)
#define LDB(O)  do{ DSR(fB[0],avB[0],O); DSR(fB[1],avB[1],O); }while(0)

#define MM0(QN) do{ \
    _Pragma("unroll") \
    for (int kk = 0; kk < 2; ++kk) \
        _Pragma("unroll") \
        for (int im = 0; im < 4; ++im) \
            acc0[QN][im] = __builtin_amdgcn_mfma_f32_16x16x32_bf16( \
                fA0[im*2+kk], fB[kk], acc0[QN][im], 0, 0, 0); \
}while(0)
#define MM1(QN) do{ \
    _Pragma("unroll") \
    for (int kk = 0; kk < 2; ++kk) \
        _Pragma("unroll") \
        for (int im = 0; im < 4; ++im) \
            acc1[QN][im] = __builtin_amdgcn_mfma_f32_16x16x32_bf16( \
                fA1[im*2+kk], fB[kk], acc1[QN][im], 0, 0, 0); \
}while(0)

#define STG_A(BF,HH,KS) do{ \
    __builtin_amdgcn_global_load_lds((const AS1 void*)(pA##HH[0] + (size_t)(KS)*64), \
        (AS3 void*)&sA[BF][HH][wb8], 16, 0, 0); \
    __builtin_amdgcn_global_load_lds((const AS1 void*)(pA##HH[1] + (size_t)(KS)*64), \
        (AS3 void*)&sA[BF][HH][4096 + wb8], 16, 0, 0); \
}while(0)
#define STG_B(BF,QN,KS) \
    __builtin_amdgcn_global_load_lds((const AS1 void*)(pB[QN] + (size_t)(KS)*64), \
        (AS3 void*)&sB[BF][QN][wb8], 16, 0, 0)

#define PH_MID do{ __builtin_amdgcn_s_barrier(); \
    asm volatile("s_waitcnt lgkmcnt(0)" ::: "memory"); \
    __builtin_amdgcn_sched_barrier(0); \
    __builtin_amdgcn_s_setprio(1); }while(0)
#define PH_END do{ __builtin_amdgcn_s_setprio(0); \
    __builtin_amdgcn_sched_barrier(0); \
    __builtin_amdgcn_s_barrier(); }while(0)
#define PH_END_VMN(N) do{ __builtin_amdgcn_s_setprio(0); \
    __builtin_amdgcn_sched_barrier(0); \
    asm volatile("s_waitcnt vmcnt(" #N ")" ::: "memory"); \
    __builtin_amdgcn_s_barrier(); }while(0)

// One qm-half of the fused epilogue: qn-outer (weights loaded once per qn),
// 32 partials live, reduce+atomic at the end. ACC = acc0/acc1, QMOFF = 0/128.
#define EPI_HALF(ACC, QMOFF) do{ \
    float pa[4][4] = {}, pb[4][4] = {}; \
    _Pragma("unroll") \
    for (int qn = 0; qn < 3; ++qn) { \
        const int i = colBase + qn*64 + wc*16 + lm; \
        const float bwa = bw2[i], bwb = bw2[H + i]; \
        const float sca = sc2[i], scb = sc2[H + i]; \
        const float4* q0 = (const float4*)(sw2 + (size_t)i * 8); \
        const float4* q1 = (const float4*)(sw2 + (size_t)(H + i) * 8); \
        const float4 wa0 = q0[0], wa1 = q0[1]; \
        const float4 wb0 = q1[0], wb1 = q1[1]; \
        _Pragma("unroll") \
        for (int im = 0; im < 4; ++im) \
        _Pragma("unroll") \
        for (int rg = 0; rg < 4; ++rg) { \
            float u = gelu_fast(ACC[qn][im][rg]); \
            float f0v = silu_f(u); \
            float bb[8]; \
            kan_bases(u, bb); \
            float t0 = bb[0]*wa0.x + bb[1]*wa0.y + bb[2]*wa0.z + bb[3]*wa0.w \
                     + bb[4]*wa1.x + bb[5]*wa1.y + bb[6]*wa1.z + bb[7]*wa1.w; \
            float t1 = bb[0]*wb0.x + bb[1]*wb0.y + bb[2]*wb0.z + bb[3]*wb0.w \
                     + bb[4]*wb1.x + bb[5]*wb1.y + bb[6]*wb1.z + bb[7]*wb1.w; \
            pa[im][rg] += fmaf(f0v, bwa, sca * t0); \
            pb[im][rg] += fmaf(f0v, bwb, scb * t1); \
        } \
    } \
    _Pragma("unroll") \
    for (int im = 0; im < 4; ++im) \
    _Pragma("unroll") \
    for (int rg = 0; rg < 4; ++rg) { \
        float a0 = pa[im][rg], a1 = pb[im][rg]; \
        _Pragma("unroll") \
        for (int off = 8; off > 0; off >>= 1) { \
            a0 += __shfl_xor(a0, off, 64); \
            a1 += __shfl_xor(a1, off, 64); \
        } \
        if (lm == 0) { \
            const int row = rowBase + (QMOFF) + wr*64 + im*16 + quad*4 + rg; \
            atomicAdd(&outp[(size_t)row * 2 + 0], a0); \
            atomicAdd(&outp[(size_t)row * 2 + 1], a1); \
        } \
    } \
}while(0)

__global__ __launch_bounds__(512, 1) void kan1_fused(
    const unsigned short* __restrict__ F, const unsigned short* __restrict__ wp,
    const float* __restrict__ bw2, const float* __restrict__ sw2,
    const float* __restrict__ sc2, float* __restrict__ outp)
{
    __shared__ __align__(16) unsigned short sA[2][2][8192];  // [buf][half 128rows][128*64]
    __shared__ __align__(16) unsigned short sB[2][3][4096];  // [buf][third 64rows][64*64]

    const int b = blockIdx.x;                  // 0..255
    const int s = b >> 3;
    const int rowT = (b & 7) * 8 + (s >> 2);   // 0..63
    const int colT = s & 3;                    // 0..3
    const int rowBase = rowT * 256, colBase = colT * 192;

    const int t = threadIdx.x;
    const int lane = t & 63;
    const int quad = lane >> 4, lm = lane & 15, p7 = lane & 7;
    const int wv = t >> 6, wr = wv & 1, wc = wv >> 1;   // 2M x 4N wave grid

    const int rr = t >> 3;                    // 0..63
    const int slotx = (t & 7) ^ (rr & 7);
    const int wb8 = (t & 448) * 8;            // wave-uniform LDS elem base (wv*512)

    const unsigned short* pA0[2]; const unsigned short* pA1[2];
    const unsigned short* pB[3];
#pragma unroll
    for (int p = 0; p < 2; ++p) {
        pA0[p] = F + (size_t)(rowBase +       p*64 + rr) * KEXP + slotx*8;
        pA1[p] = F + (size_t)(rowBase + 128 + p*64 + rr) * KEXP + slotx*8;
    }
#pragma unroll
    for (int q = 0; q < 3; ++q)
        pB[q] = wp + (size_t)(colBase + q*64 + rr) * KEXP + slotx*8;

    unsigned int avA[8], avB[2];
    {
        unsigned int aB = (unsigned int)(size_t)(AS3 unsigned short*)&sA[0][0][0];
        unsigned int bB = (unsigned int)(size_t)(AS3 unsigned short*)&sB[0][0][0];
#pragma unroll
        for (int im = 0; im < 4; ++im)
#pragma unroll
            for (int kk = 0; kk < 2; ++kk)
                avA[im*2+kk] = aB + (unsigned)(((wr*64 + im*16 + lm)*64 + (((kk*4+quad)^p7)*8)) * 2);
#pragma unroll
        for (int kk = 0; kk < 2; ++kk)
            avB[kk] = bB + (unsigned)(((wc*16 + lm)*64 + (((kk*4+quad)^p7)*8)) * 2);
    }

    floatx4 acc0[3][4] = {};   // [qn][im], qm=0 rows
    floatx4 acc1[3][4] = {};   // qm=1 rows
    bhalf8 fA0[8], fA1[8], fB[2];

    // prologue: buf0 <- ks0 (7 loads), buf1 <- ks1 minus B2 (6 loads); retire 5
    STG_A(0,0,0); STG_A(0,1,0); STG_B(0,0,0); STG_B(0,1,0); STG_B(0,2,0);
    STG_A(1,0,1); STG_A(1,1,1); STG_B(1,0,1); STG_B(1,1,1);
    asm volatile("s_waitcnt vmcnt(8)" ::: "memory");
    __builtin_amdgcn_s_barrier();

#pragma unroll 1
    for (int i = 0; i < NITER; ++i) {
        const int k1 = 2*i + 1;
        const int k2 = (2*i + 2 > 107) ? 107 : 2*i + 2;
        const int k3 = (2*i + 3 > 107) ? 107 : 2*i + 3;
        // K-step 2i from buf0
        LDA0(0);     LDB(0);     STG_B(1,2,k1);               PH_MID; MM0(0);         PH_END_VMN(10);
        LDA1(16384);             STG_A(0,0,k2);               PH_MID; MM1(0);         PH_END_VMN(10);
        LDB(8192);               STG_A(0,1,k2);               PH_MID; MM1(1); MM0(1); PH_END_VMN(11);
        LDB(16384);              STG_B(0,0,k2); STG_B(0,1,k2);PH_MID; MM0(2); MM1(2); PH_END_VMN(8);
        // K-step 2i+1 from buf1
        LDA0(32768); LDB(24576); STG_B(0,2,k2);               PH_MID; MM0(0);         PH_END;
        LDA1(49152);             STG_A(1,0,k3);               PH_MID; MM1(0);         PH_END_VMN(10);
        LDB(32768);              STG_A(1,1,k3);               PH_MID; MM1(1); MM0(1); PH_END_VMN(11);
        LDB(40960);              STG_B(1,0,k3); STG_B(1,1,k3);PH_MID; MM0(2); MM1(2); PH_END_VMN(8);
    }

    // ---- fused layer-2 epilogue: two sequential low-pressure half-passes ----
    EPI_HALF(acc0, 0);
    EPI_HALF(acc1, 128);
}

extern "C" void kernel_launch(void* const* d_in, const int* in_sizes, int n_in,
                              void* d_out, int out_size, void* d_ws, size_t ws_size,
                              hipStream_t stream) {
    const float* hidden = (const float*)d_in[0];
    const float* bw1    = (const float*)d_in[1];
    const float* sw1    = (const float*)d_in[2];
    const float* sc1    = (const float*)d_in[3];
    const float* bw2    = (const float*)d_in[4];
    const float* sw2    = (const float*)d_in[5];
    const float* sc2    = (const float*)d_in[6];
    float* out = (float*)d_out;

    const size_t wp_elems = (size_t)H * KEXP;      // 10.6 MB bf16
    unsigned short* wp = (unsigned short*)d_ws;
    unsigned short* F  = wp + wp_elems;            // 226.5 MB bf16

    hipMemsetAsync(d_out, 0, (size_t)out_size, stream);   // graph-capturable
    prep_expand<<<6144 + H, 256, 0, stream>>>(hidden, bw1, sw1, sc1, wp, F);
    kan1_fused<<<256, 512, 0, stream>>>(F, wp, bw2, sw2, sc2, out);
}